// Round 8
// baseline (2046.845 us; speedup 1.0000x reference)
//
#include <hip/hip_runtime.h>
#include <cstdint>
#include <cstddef>

// Problem constants
#define SENC  128
#define NSTEPS 159          // 128 encoder + 31 decoder
#define HB16  524288        // shorts per h slot (1 MB), tile-major [r][c][128][16]
#define XSLICE 131072       // shorts per r-slice within a slot: 64 tiles x 2048
#define SLAB_ELEMS 55296    // per-c W_hi slab: 36*3*64*8 shorts
#define FRAG_TOTAL 442368   // 64*36*3*64 fragment slots
#define FS 16               // flag stride in dwords (64B lines)

typedef short  short8  __attribute__((ext_vector_type(8)));
typedef float  floatx4 __attribute__((ext_vector_type(4)));
typedef float  f32x4   __attribute__((ext_vector_type(4)));
typedef int    i32x4   __attribute__((ext_vector_type(4)));
typedef unsigned long long u64;

#define MFMA(a, b, c) __builtin_amdgcn_mfma_f32_16x16x32_bf16((a), (b), (c), 0, 0, 0)

// ---------- raw asm memory ops ----------
__device__ __forceinline__ i32x4 ld_nc16(const void* p) {      // bypass L1+L2 (coherence point)
    i32x4 r;
    asm volatile("global_load_dwordx4 %0, %1, off sc0 sc1" : "=&v"(r) : "v"(p) : "memory");
    return r;
}
__device__ __forceinline__ i32x4 ld_sc0_16(const void* p) {    // bypass L1, cache in local L2
    i32x4 r;
    asm volatile("global_load_dwordx4 %0, %1, off sc0" : "=&v"(r) : "v"(p) : "memory");
    return r;
}
__device__ __forceinline__ i32x4 ld_c16(const void* p) {       // plain cached load (read-only data)
    i32x4 r;
    asm volatile("global_load_dwordx4 %0, %1, off" : "=&v"(r) : "v"(p) : "memory");
    return r;
}
// Far-atomic publish (R5): no-return atomic swap executes at the coherence
// point; drain is deferred into next-step region1.
__device__ __forceinline__ void st_swap8(void* p, u64 v) {
    asm volatile("global_atomic_swap_x2 %0, %1, off sc1" :: "v"(p), "v"(v) : "memory");
}
__device__ __forceinline__ void st_swap4(void* p, unsigned v) {
    asm volatile("global_atomic_swap %0, %1, off sc1" :: "v"(p), "v"(v) : "memory");
}
#define WAITVM(N) asm volatile("s_waitcnt vmcnt(" #N ")" ::: "memory")
#define WAITLGKM  asm volatile("s_waitcnt lgkmcnt(0)" ::: "memory")

// ---------- agent-scope relaxed atomics ----------
__device__ __forceinline__ unsigned ldu_dev(const unsigned* p) {
    return __hip_atomic_load(p, __ATOMIC_RELAXED, __HIP_MEMORY_SCOPE_AGENT);
}
__device__ __forceinline__ u64 ldq_dev(const u64* p) {
    return __hip_atomic_load(p, __ATOMIC_RELAXED, __HIP_MEMORY_SCOPE_AGENT);
}
__device__ __forceinline__ void stu_dev(unsigned* p, unsigned v) {
    __hip_atomic_store(p, v, __ATOMIC_RELAXED, __HIP_MEMORY_SCOPE_AGENT);
}

// ---------- workgroup-scope LDS atomics ----------
__device__ __forceinline__ unsigned ld_ws(const unsigned* p) {
    return __hip_atomic_load(p, __ATOMIC_RELAXED, __HIP_MEMORY_SCOPE_WORKGROUP);
}
__device__ __forceinline__ void st_ws(unsigned* p, unsigned v) {
    __hip_atomic_store(p, v, __ATOMIC_RELAXED, __HIP_MEMORY_SCOPE_WORKGROUP);
}
__device__ __forceinline__ unsigned add_ws(unsigned* p, unsigned v) {
    return __hip_atomic_fetch_add(p, v, __ATOMIC_RELAXED, __HIP_MEMORY_SCOPE_WORKGROUP);
}

// ---------- bf16 helpers (RNE) ----------
__device__ __forceinline__ float bf2f(short s) {
    return __uint_as_float(((unsigned)(unsigned short)s) << 16);
}
__device__ __forceinline__ short f2bf(float f) {
    unsigned u = __float_as_uint(f);
    return (short)((u + 0x7FFFu + ((u >> 16) & 1u)) >> 16);
}
__device__ __forceinline__ void f2pair(float f, short& hi, short& lo) {
    hi = f2bf(f);
    lo = f2bf(f - bf2f(hi));
}

__device__ __forceinline__ float sigm(float x) {
    return 1.0f / (1.0f + __expf(-x));
}
__device__ __forceinline__ float tanh_fast(float x) {
    float cx = fminf(fmaxf(x, -15.0f), 15.0f);
    float e = __expf(2.0f * cx);
    return (e - 1.0f) / (e + 1.0f);
}

// ---------- setup: swizzle W_hi (all K) + Wi_lo (x-part only) into fragment order ----------
__global__ void setup_swizzle(const float* __restrict__ Wi, const float* __restrict__ Wh,
                              short* __restrict__ whi, short* __restrict__ wlo_x) {
    const int idx = blockIdx.x * 256 + threadIdx.x;
    if (idx >= FRAG_TOTAL) return;
    const int l    = idx & 63;
    const int rest = idx >> 6;
    const int t    = rest % 3;
    const int ki   = (rest / 3) % 36;
    const int c    = rest / 108;
    const int nrow = t * 1024 + c * 16 + (l & 15);
    const int kb   = ki * 32 + (l >> 4) * 8;
    short8 vh, vl;
#pragma unroll
    for (int j = 0; j < 8; ++j) {
        const int k = kb + j;
        float w = (k < 128) ? Wi[(size_t)nrow * 128 + k]
                            : Wh[(size_t)nrow * 1024 + (k - 128)];
        short h, lo2;
        f2pair(w, h, lo2);
        vh[j] = h; vl[j] = lo2;
    }
    *(short8*)(whi + (size_t)idx * 8) = vh;
    if (ki < 4) {
        const int xi = ((c * 4 + ki) * 3 + t) * 64 + l;
        *(short8*)(wlo_x + (size_t)xi * 8) = vl;
    }
}

// ---------- region-2 core macros (literal hb indices, runtime addrs) ----------
#define HCONS(S, KI) do { \
    short8 ah_ = *(short8*)&hb[S]; \
    const int fo_ = (((KI) * 3) * 64 + lane) * 8; \
    short8 b0_ = *(const short8*)(s_whi + fo_); \
    short8 b1_ = *(const short8*)(s_whi + fo_ + 512); \
    short8 b2_ = *(const short8*)(s_whi + fo_ + 1024); \
    aR  = MFMA(ah_, b0_, aR); \
    aZ  = MFMA(ah_, b1_, aZ); \
    aNh = MFMA(ah_, b2_, aNh); \
} while (0)

#define CH_ISSUE(LDFN, B, KC) do { \
    const short* hp_ = hrd + (size_t)(KC) * 16384; \
    hb[(B) + 0] = LDFN(hp_); \
    hb[(B) + 1] = LDFN(hp_ + 4096); \
    hb[(B) + 2] = LDFN(hp_ + 8192); \
    hb[(B) + 3] = LDFN(hp_ + 12288); \
} while (0)

#define CH_CONS(B, KC) do { \
    const int kb_ = 4 + 4 * (KC); \
    HCONS((B) + 0, kb_ + 0); \
    HCONS((B) + 1, kb_ + 1); \
    HCONS((B) + 2, kb_ + 2); \
    HCONS((B) + 3, kb_ + 3); \
} while (0)

#define SPIN_CH(KC) do { \
    while (ld_ws(&s_sub[KC]) < (unsigned)step) __builtin_amdgcn_s_sleep(2); \
} while (0)

// ---------- region-1 helpers ----------
#define R1CORE(KI, AH, AL) do { \
    const int fo_ = (((KI) * 3) * 64 + lane) * 8; \
    short8 b0_ = *(const short8*)(s_whi + fo_); \
    short8 b1_ = *(const short8*)(s_whi + fo_ + 512); \
    short8 b2_ = *(const short8*)(s_whi + fo_ + 1024); \
    aR  = MFMA(AH, b0_, aR);  aR  = MFMA(AH, L0r[KI], aR);  aR  = MFMA(AL, b0_, aR); \
    aZ  = MFMA(AH, b1_, aZ);  aZ  = MFMA(AH, L1r[KI], aZ);  aZ  = MFMA(AL, b1_, aZ); \
    aNi = MFMA(AH, b2_, aNi); aNi = MFMA(AH, L2r[KI], aNi); aNi = MFMA(AL, b2_, aNi); \
} while (0)

#define R1TRIPLE(KI) do { \
    short8 ah_, al_; \
    _Pragma("unroll") \
    for (int j = 0; j < 8; ++j) { short h2_, l2_; f2pair(f[j], h2_, l2_); ah_[j] = h2_; al_[j] = l2_; } \
    R1CORE(KI, ah_, al_); \
} while (0)

// raw variant: inputs from two asm-loaded i32x4 (f32 data)
#define R1RAW(KI, V0, V1) do { \
    f32x4 fa_ = *(f32x4*)&(V0); \
    f32x4 fb_ = *(f32x4*)&(V1); \
    short8 ah_, al_; \
    _Pragma("unroll") \
    for (int j = 0; j < 4; ++j) { \
        short h2_, l2_; \
        f2pair(fa_[j], h2_, l2_); ah_[j] = h2_;     al_[j] = l2_; \
        f2pair(fb_[j], h2_, l2_); ah_[4 + j] = h2_; al_[4 + j] = l2_; \
    } \
    R1CORE(KI, ah_, al_); \
} while (0)

#define LOADF(KI) do { \
    const float* s_ = feats + ((size_t)brow * 159 + step) * 64 + (KI) * 32 + q * 8; \
    f32x4 a_ = ((const f32x4*)s_)[0], b_ = ((const f32x4*)s_)[1]; \
    _Pragma("unroll") for (int j = 0; j < 4; ++j) { f[j] = a_[j]; f[4 + j] = b_[j]; } \
} while (0)

#define LOADL(KI) do { \
    const float* s_ = labels + ((size_t)brow * 128 + step) * 64 + ((KI) - 2) * 32 + q * 8; \
    f32x4 a_ = ((const f32x4*)s_)[0], b_ = ((const f32x4*)s_)[1]; \
    _Pragma("unroll") for (int j = 0; j < 4; ++j) { f[j] = a_[j]; f[4 + j] = b_[j]; } \
} while (0)

#define LOADP(KI) do { \
    const u64* pp_ = (const u64*)(ps_f32 + (size_t)brow * 64 + ((KI) - 2) * 32 + q * 8); \
    _Pragma("unroll") for (int j = 0; j < 4; ++j) { \
        u64 v_ = ldq_dev(pp_ + j); \
        f[2 * j]     = __uint_as_float((unsigned)v_); \
        f[2 * j + 1] = __uint_as_float((unsigned)(v_ >> 32)); } \
} while (0)

// ---------- FUSED encoder step: region2 load latency under region1 compute ----------
// Manual wave-level vmcnt schedule. Issue order (22 loads):
//   [LF1 x2, LL2 x2, LL3 x2, k0 x4, k1 x4, k2 x4, k3 x4]
// WAITVM(20)->LF1, (18)->LL2, (16)->LL3 (triples 1-3 compute = k0-k3 cover),
// then rolling (12)->k0+issue k4 ... (0)->k7, identical tail to R5's REGION2.
// The conditional flag store (one wave, oldest in queue) only makes that
// wave's waits stricter -> safe. Compiler-visible loads are excluded from
// this window (triple0 + poll complete beforehand).
#define REGION12(LDFN) do { \
    i32x4 xb0, xb1, xb2, xb3, xb4, xb5; \
    i32x4 hb[16]; \
    const float* sF_  = feats  + ((size_t)brow * 159 + step) * 64 + 32 + q * 8; \
    const float* sL2_ = labels + ((size_t)brow * 128 + step) * 64 + q * 8; \
    const float* sL3_ = labels + ((size_t)brow * 128 + step) * 64 + 32 + q * 8; \
    xb0 = ld_c16(sF_);      xb1 = ld_c16(sF_ + 4); \
    xb2 = ld_c16(sL2_);     xb3 = ld_c16(sL2_ + 4); \
    xb4 = ld_c16(sL3_);     xb5 = ld_c16(sL3_ + 4); \
    const int k0_ = r0;            const int k1_ = (r0 + 1) & 7; \
    const int k2_ = (r0 + 2) & 7;  const int k3_ = (r0 + 3) & 7; \
    const int k4_ = (r0 + 4) & 7;  const int k5_ = (r0 + 5) & 7; \
    const int k6_ = (r0 + 6) & 7;  const int k7_ = (r0 + 7) & 7; \
    SPIN_CH(k0_); CH_ISSUE(LDFN, 0,  k0_); \
    SPIN_CH(k1_); CH_ISSUE(LDFN, 4,  k1_); \
    SPIN_CH(k2_); CH_ISSUE(LDFN, 8,  k2_); \
    SPIN_CH(k3_); CH_ISSUE(LDFN, 12, k3_); \
    WAITVM(20); R1RAW(1, xb0, xb1); \
    WAITVM(18); R1RAW(2, xb2, xb3); \
    WAITVM(16); R1RAW(3, xb4, xb5); \
    WAITVM(12); CH_CONS(0,  k0_); SPIN_CH(k4_); CH_ISSUE(LDFN, 0,  k4_); \
    WAITVM(12); CH_CONS(4,  k1_); SPIN_CH(k5_); CH_ISSUE(LDFN, 4,  k5_); \
    WAITVM(12); CH_CONS(8,  k2_); SPIN_CH(k6_); CH_ISSUE(LDFN, 8,  k6_); \
    WAITVM(12); CH_CONS(12, k3_); SPIN_CH(k7_); CH_ISSUE(LDFN, 12, k7_); \
    WAITVM(12); CH_CONS(0,  k4_); \
    WAITVM(8);  CH_CONS(4,  k5_); \
    WAITVM(4);  CH_CONS(8,  k6_); \
    WAITVM(0);  CH_CONS(12, k7_); \
} while (0)

// decoder/fallback region2 (R5 verbatim)
#define REGION2(LDFN) do { \
    i32x4 hb[16]; \
    const int k0_ = r0;            const int k1_ = (r0 + 1) & 7; \
    const int k2_ = (r0 + 2) & 7;  const int k3_ = (r0 + 3) & 7; \
    const int k4_ = (r0 + 4) & 7;  const int k5_ = (r0 + 5) & 7; \
    const int k6_ = (r0 + 6) & 7;  const int k7_ = (r0 + 7) & 7; \
    SPIN_CH(k0_); CH_ISSUE(LDFN, 0,  k0_); \
    SPIN_CH(k1_); CH_ISSUE(LDFN, 4,  k1_); \
    SPIN_CH(k2_); CH_ISSUE(LDFN, 8,  k2_); \
    SPIN_CH(k3_); CH_ISSUE(LDFN, 12, k3_); \
    WAITVM(12); CH_CONS(0,  k0_); SPIN_CH(k4_); CH_ISSUE(LDFN, 0,  k4_); \
    WAITVM(12); CH_CONS(4,  k1_); SPIN_CH(k5_); CH_ISSUE(LDFN, 4,  k5_); \
    WAITVM(12); CH_CONS(8,  k2_); SPIN_CH(k6_); CH_ISSUE(LDFN, 8,  k6_); \
    WAITVM(12); CH_CONS(12, k3_); SPIN_CH(k7_); CH_ISSUE(LDFN, 12, k7_); \
    WAITVM(12); CH_CONS(0,  k4_); \
    WAITVM(8);  CH_CONS(4,  k5_); \
    WAITVM(4);  CH_CONS(8,  k6_); \
    WAITVM(0);  CH_CONS(12, k7_); \
} while (0)

// ---------- main persistent kernel ----------
// Sync design (fresh-slot broadcast + decoupled waves, R5 skeleton):
//  - h(t) in its OWN 1 MB slot; far-atomic swap publish, drain deferred;
//    consumer sc0 loads -> XCD-L2 multicast of MALL lines.
//  - Encoder steps (fused): triple0 (covers swap drain) -> finalize+flag ->
//    per-wave hfp poll -> REGION12 (region2 loads issued FIRST, triples 1-3
//    compute as MALL-latency cover, rolling consume).
//  - Decoder steps: R5 path (pflag wait + barrier, LOADP, then region2).
//  - ps-steps publish immediately; ring-2 fallback WAR transitivity as R5.
__global__ __launch_bounds__(512, 2) void gru_main(
    const float* __restrict__ feats, const float* __restrict__ labels,
    const float* __restrict__ bi,    const float* __restrict__ bh,
    const float* __restrict__ Wd,    const float* __restrict__ bd,
    const short* __restrict__ whi_sw, const short* __restrict__ wlo_x,
    short* __restrict__ h16,         float* __restrict__ ps_f32,
    float* __restrict__ out,
    unsigned* __restrict__ hflag,    // [4r][64c] @64B
    unsigned* __restrict__ pflag,    // [4r][64c] @64B
    int nslots)                      // 160 = fresh-per-step (cached), 2 = ring (nc)
{
    __shared__ short s_whi[SLAB_ELEMS];   // 108 KB resident W_hi slab (fragment order)
    __shared__ float s_ps[2048];          // ps-phase h staging (2 rows x 1024)
    __shared__ short s_tr[8][16][18];     // epilogue transpose tiles (padded: bank-safe)
    __shared__ unsigned s_sub[8];         // chunk ready: latest step confirmed
    __shared__ unsigned s_arrD, s_arrI;   // publish arrival counters (deferred/immediate)

    const int tid  = threadIdx.x;
    const int lane = tid & 63;
    const int wv   = tid >> 6;            // wave 0..7
    const int q    = lane >> 4;
    const int n16  = lane & 15;
    const int c    = blockIdx.x & 63;     // out-group: h-cols [16c, 16c+16)
    const int r    = blockIdx.x >> 6;     // batch-group: rows [128r, 128r+128)
    const int r0   = c & 7;               // XCD id: rotation start chunk
    const bool cached = (nslots > 2);

    // init sync state + stage W_hi slab
    if (tid < 8) s_sub[tid] = 0;
    if (tid == 8) s_arrD = 0;
    if (tid == 9) s_arrI = 0;
    {
        const f32x4* src = (const f32x4*)(whi_sw + (size_t)c * SLAB_ELEMS);
        f32x4* dst = (f32x4*)s_whi;
        for (int i = tid; i < SLAB_ELEMS / 8; i += 512) dst[i] = src[i];
    }
    __syncthreads();

    const int mbase = r * 128 + wv * 16;  // this wave's 16 batch rows (global)
    const int brow  = mbase + n16;        // A-fragment row for this lane
    const int row_r = c * 16 + n16;       // gate row == D col
    const float bias_r  = bi[row_r] + bh[row_r];
    const float bias_z  = bi[1024 + row_r] + bh[1024 + row_r];
    const float bias_ni = bi[2048 + row_r];
    const float bias_nh = bh[2048 + row_r];

    unsigned* my_hflag = hflag + (r * 64 + c) * FS;
    unsigned* my_pflag = pflag + (r * 64 + c) * FS;
    const unsigned* hfp     = hflag + (r * 64 + 8 * wv + (lane & 7)) * FS;  // wave's 8 producers
    const unsigned* grp_hfl = hflag + (r * 64) * FS;
    const unsigned* grp_pfl = pflag + (r * 64) * FS;

    // hoist region-1 W_lo fragments (step-invariant): 12 x short8 = 48 VGPRs
    short8 L0r[4], L1r[4], L2r[4];
#pragma unroll
    for (int ki = 0; ki < 4; ++ki) {
        const short* base = wlo_x + (size_t)(((c * 4 + ki) * 3) * 64 + lane) * 8;
        L0r[ki] = *(const short8*)(base);
        L1r[ki] = *(const short8*)(base + 512);
        L2r[ki] = *(const short8*)(base + 1024);
    }

    float hold[4] = {0.f, 0.f, 0.f, 0.f};  // h carried fp32 in-register

    for (int step = 0; step < NSTEPS; ++step) {
        const bool dec = (step >= SENC);
        const unsigned tgt = (unsigned)(step + 1);
        const int rslot = cached ? step       : (step & 1);
        const int wslot = cached ? (step + 1) : ((step + 1) & 1);
        const short* hrd = h16 + (size_t)rslot * HB16 + (size_t)r * XSLICE
                         + (size_t)(wv * 16 + n16) * 16 + (q & 1) * 8 + (q >> 1) * 2048;
        short* hwr = h16 + (size_t)wslot * HB16 + (size_t)r * XSLICE;

        floatx4 aR  = (floatx4){bias_r,  bias_r,  bias_r,  bias_r};
        floatx4 aZ  = (floatx4){bias_z,  bias_z,  bias_z,  bias_z};
        floatx4 aNi = (floatx4){bias_ni, bias_ni, bias_ni, bias_ni};
        floatx4 aNh = (floatx4){bias_nh, bias_nh, bias_nh, bias_nh};

        if (step == 0) {
            // ---- step 0: x-part only, no region2, no finalize ----
            float f[8];
            LOADF(0); R1TRIPLE(0);
            LOADF(1); R1TRIPLE(1);
            LOADL(2); R1TRIPLE(2);
            LOADL(3); R1TRIPLE(3);
        } else if (!dec) {
            // ---- FUSED encoder step (1..127) ----
            {
                float f[8];
                LOADF(0); R1TRIPLE(0);   // compiler loads: incidentally drain swaps
            }
            // finalize h(step) publish (swaps issued at epilogue of step-1)
            WAITVM(0);
            if (lane == 0) {
                unsigned old = add_ws(&s_arrD, 1u);
                if (old == 8u * (unsigned)step - 1u)
                    stu_dev(my_hflag, (unsigned)step);
            }
            // per-wave h-ready poll (peers set flag at the same program point)
            while (!__all(ldu_dev(hfp) >= (unsigned)step))
                __builtin_amdgcn_s_sleep(2);
            if (lane == 0) st_ws(&s_sub[wv], (unsigned)step);
            // region2 loads issued first; triples 1-3 hide the MALL RT
            if (cached) { REGION12(ld_sc0_16); }
            else        { REGION12(ld_nc16); }
        } else {
            // ---- decoder step (R5 path) ----
            {
                float f[8];
                LOADF(0); R1TRIPLE(0);
                LOADF(1); R1TRIPLE(1);
                // ps(step) published during step-1's ps phase
                if (wv == 0) {
                    while (ldu_dev(grp_pfl + lane * FS) < (unsigned)step)
                        __builtin_amdgcn_s_sleep(2);
                }
                __syncthreads();
                LOADP(2); R1TRIPLE(2);
                LOADP(3); R1TRIPLE(3);
            }
            while (!__all(ldu_dev(hfp) >= (unsigned)step))
                __builtin_amdgcn_s_sleep(2);
            if (lane == 0) st_ws(&s_sub[wv], (unsigned)step);
            if (cached) { REGION2(ld_sc0_16); }
            else        { REGION2(ld_nc16); }
        }

        // ---- epilogue: GRU update; far-atomic publish of own tile ----
        {
#pragma unroll
            for (int i = 0; i < 4; ++i) {
                float rr = sigm(aR[i]);
                float zz = sigm(aZ[i]);
                float nn = tanh_fast(aNi[i] + rr * aNh[i]);
                float hv = (1.0f - zz) * nn + zz * hold[i];
                hold[i] = hv;
                s_tr[wv][q * 4 + i][n16] = f2bf(hv);   // D row = q*4+i, col = n16
            }
            WAITLGKM;
            const int rr2 = lane >> 2, seg = lane & 3;
            u64 v = *(const u64*)&s_tr[wv][rr2][seg * 4];
            st_swap8(hwr + (size_t)c * 2048 + (size_t)(wv * 16 + rr2) * 16 + seg * 4, v);
            if (step >= SENC - 1) {                    // immediate publish (ps needs it)
                WAITVM(0);
                if (lane == 0) {
                    unsigned old = add_ws(&s_arrI, 1u);
                    if (old == 8u * (unsigned)(step - (SENC - 1) + 1) - 1u)
                        stu_dev(my_hflag, tgt);
                }
            }
        }

        // ---- ps phase: after encoder (step 127) and every decoder step ----
        if (step >= SENC - 1) {
            const int ot = step - (SENC - 1);          // output time 0..31
            const int prow0 = r * 128 + 2 * c;         // this block's 2 ps rows (global)
            if (wv == 0) {                              // need ALL producers' h rows
                while (ldu_dev(grp_hfl + lane * FS) < tgt)
                    __builtin_amdgcn_s_sleep(2);
            }
            __syncthreads();
            if (tid < 256) {                            // 2 rows x 1024 cols, tile-major gather
                const int rl = tid >> 7, rest = tid & 127;
                const int ct = rest >> 1, half = rest & 1;
                const short* src = hwr + (size_t)ct * 2048
                                 + (size_t)(2 * c + rl) * 16 + half * 8;
                i32x4 v = ld_nc16(src);
                WAITVM(0);
                short8 s = *(short8*)&v;
#pragma unroll
                for (int j = 0; j < 8; ++j)
                    s_ps[rl * 1024 + ct * 16 + half * 8 + j] = bf2f(s[j]);
            }
            __syncthreads();
            // dedup'd dot: each thread does BOTH rows for (o, K-eighth e)
            const int o = tid >> 3, e = tid & 7;
            const float* wrow = Wd + (size_t)o * 1024;
            float acc0 = 0.0f, acc1 = 0.0f;
#pragma unroll 8
            for (int j = 0; j < 32; ++j) {
                const int k = j * 32 + e * 4;
                f32x4 w  = *(const f32x4*)(wrow + k);
                f32x4 a4 = *(const f32x4*)(s_ps + k);
                f32x4 b4 = *(const f32x4*)(s_ps + 1024 + k);
                acc0 += a4[0] * w[0] + a4[1] * w[1] + a4[2] * w[2] + a4[3] * w[3];
                acc1 += b4[0] * w[0] + b4[1] * w[1] + b4[2] * w[2] + b4[3] * w[3];
            }
            acc0 += __shfl_xor(acc0, 1); acc0 += __shfl_xor(acc0, 2); acc0 += __shfl_xor(acc0, 4);
            acc1 += __shfl_xor(acc1, 1); acc1 += __shfl_xor(acc1, 2); acc1 += __shfl_xor(acc1, 4);
            if (e == 0) {
                float v0 = acc0 + bd[o];
                float v1 = acc1 + bd[o];
                out[((size_t)ot * 512 + prow0)     * 64 + o] = v0;
                out[((size_t)ot * 512 + prow0 + 1) * 64 + o] = v1;
                st_swap4(ps_f32 + (size_t)prow0       * 64 + o, __float_as_uint(v0));
                st_swap4(ps_f32 + (size_t)(prow0 + 1) * 64 + o, __float_as_uint(v1));
            }
            WAITVM(0);
            __syncthreads();
            if (tid == 0) stu_dev(my_pflag, tgt);      // ps(step+1) published
        }
    }
}

extern "C" void kernel_launch(void* const* d_in, const int* in_sizes, int n_in,
                              void* d_out, int out_size, void* d_ws, size_t ws_size,
                              hipStream_t stream) {
    const float* feats  = (const float*)d_in[0];
    const float* labels = (const float*)d_in[1];
    const float* Wi     = (const float*)d_in[2];
    const float* Wh     = (const float*)d_in[3];
    const float* bi     = (const float*)d_in[4];
    const float* bh     = (const float*)d_in[5];
    const float* Wd     = (const float*)d_in[6];
    const float* bd     = (const float*)d_in[7];
    float* out = (float*)d_out;

    char* ws = (char*)d_ws;
    short*    whi_sw = (short*)(ws);                   //  7,077,888 B
    short*    wlo_x  = (short*)(ws + 7077888);         //    786,432 B
    float*    ps_f32 = (float*)(ws + 7864320);         //    131,072 B
    unsigned* pflag  = (unsigned*)(ws + 7995392);      //     16,384 B (4r x 64c x 64B)
    unsigned* hflag  = (unsigned*)(ws + 8011776);      //     16,384 B (4r x 64c x 64B)
    short*    h16    = (short*)(ws + 8388608);         //  nslots x 1 MB h slots

    // cached mode needs slots 0..159 (slot t = h(t)); fallback = 2-slot ring + nc reads
    const size_t need = 8388608ull + 160ull * 1048576ull;  // 176,160,768 B
    int nslots = (ws_size >= need) ? 160 : 2;

    // zero flag state (pflag + hflag)
    hipMemsetAsync(ws + 7995392, 0, 32768, stream);

    setup_swizzle<<<FRAG_TOTAL / 256, 256, 0, stream>>>(Wi, Wh, whi_sw, wlo_x);

    void* args[] = {(void*)&feats, (void*)&labels, (void*)&bi, (void*)&bh,
                    (void*)&Wd, (void*)&bd, (void*)&whi_sw, (void*)&wlo_x,
                    (void*)&h16, (void*)&ps_f32, (void*)&out,
                    (void*)&hflag, (void*)&pflag, (void*)&nslots};
    hipLaunchCooperativeKernel(reinterpret_cast<void*>(gru_main),
                               dim3(256), dim3(512), args, 0, stream);
}

// Round 9
// 1409.717 us; speedup vs baseline: 1.4520x; 1.4520x over previous
//
#include <hip/hip_runtime.h>
#include <cstdint>
#include <cstddef>

// Problem constants
#define SENC  128
#define NSTEPS 159          // 128 encoder + 31 decoder
#define HB16  524288        // shorts per h slot (1 MB), tile-major [r][c][128][16]
#define XSLICE 131072       // shorts per r-slice within a slot: 64 tiles x 2048
#define SLAB_ELEMS 55296    // per-c W_hi slab: 36*3*64*8 shorts
#define FRAG_TOTAL 442368   // 64*36*3*64 fragment slots
#define FS 16               // flag stride in dwords (64B lines)

typedef short  short8  __attribute__((ext_vector_type(8)));
typedef float  floatx4 __attribute__((ext_vector_type(4)));
typedef float  f32x4   __attribute__((ext_vector_type(4)));
typedef int    i32x4   __attribute__((ext_vector_type(4)));
typedef unsigned long long u64;

#define MFMA(a, b, c) __builtin_amdgcn_mfma_f32_16x16x32_bf16((a), (b), (c), 0, 0, 0)

// ---------- raw asm memory ops ----------
__device__ __forceinline__ i32x4 ld_nc16(const void* p) {      // bypass L1+L2 (coherence point)
    i32x4 r;
    asm volatile("global_load_dwordx4 %0, %1, off sc0 sc1" : "=&v"(r) : "v"(p) : "memory");
    return r;
}
__device__ __forceinline__ i32x4 ld_sc0_16(const void* p) {    // bypass L1, cache in local L2
    i32x4 r;
    asm volatile("global_load_dwordx4 %0, %1, off sc0" : "=&v"(r) : "v"(p) : "memory");
    return r;
}
// Far-atomic publish (R5): no-return atomic swap executes at the coherence
// point; drain is deferred into next-step region1.
__device__ __forceinline__ void st_swap8(void* p, u64 v) {
    asm volatile("global_atomic_swap_x2 %0, %1, off sc1" :: "v"(p), "v"(v) : "memory");
}
__device__ __forceinline__ void st_swap4(void* p, unsigned v) {
    asm volatile("global_atomic_swap %0, %1, off sc1" :: "v"(p), "v"(v) : "memory");
}
#define WAITVM(N) asm volatile("s_waitcnt vmcnt(" #N ")" ::: "memory")
#define WAITLGKM  asm volatile("s_waitcnt lgkmcnt(0)" ::: "memory")

// ---------- agent-scope relaxed atomics ----------
__device__ __forceinline__ unsigned ldu_dev(const unsigned* p) {
    return __hip_atomic_load(p, __ATOMIC_RELAXED, __HIP_MEMORY_SCOPE_AGENT);
}
__device__ __forceinline__ u64 ldq_dev(const u64* p) {
    return __hip_atomic_load(p, __ATOMIC_RELAXED, __HIP_MEMORY_SCOPE_AGENT);
}
__device__ __forceinline__ void stu_dev(unsigned* p, unsigned v) {
    __hip_atomic_store(p, v, __ATOMIC_RELAXED, __HIP_MEMORY_SCOPE_AGENT);
}

// ---------- workgroup-scope LDS atomics ----------
__device__ __forceinline__ unsigned ld_ws(const unsigned* p) {
    return __hip_atomic_load(p, __ATOMIC_RELAXED, __HIP_MEMORY_SCOPE_WORKGROUP);
}
__device__ __forceinline__ void st_ws(unsigned* p, unsigned v) {
    __hip_atomic_store(p, v, __ATOMIC_RELAXED, __HIP_MEMORY_SCOPE_WORKGROUP);
}
__device__ __forceinline__ unsigned add_ws(unsigned* p, unsigned v) {
    return __hip_atomic_fetch_add(p, v, __ATOMIC_RELAXED, __HIP_MEMORY_SCOPE_WORKGROUP);
}

// ---------- bf16 helpers (RNE) ----------
__device__ __forceinline__ float bf2f(short s) {
    return __uint_as_float(((unsigned)(unsigned short)s) << 16);
}
__device__ __forceinline__ short f2bf(float f) {
    unsigned u = __float_as_uint(f);
    return (short)((u + 0x7FFFu + ((u >> 16) & 1u)) >> 16);
}
__device__ __forceinline__ void f2pair(float f, short& hi, short& lo) {
    hi = f2bf(f);
    lo = f2bf(f - bf2f(hi));
}

__device__ __forceinline__ float sigm(float x) {
    return 1.0f / (1.0f + __expf(-x));
}
__device__ __forceinline__ float tanh_fast(float x) {
    float cx = fminf(fmaxf(x, -15.0f), 15.0f);
    float e = __expf(2.0f * cx);
    return (e - 1.0f) / (e + 1.0f);
}

// ---------- setup: swizzle W_hi (all K) + Wi_lo (x-part only) into fragment order ----------
__global__ void setup_swizzle(const float* __restrict__ Wi, const float* __restrict__ Wh,
                              short* __restrict__ whi, short* __restrict__ wlo_x) {
    const int idx = blockIdx.x * 256 + threadIdx.x;
    if (idx >= FRAG_TOTAL) return;
    const int l    = idx & 63;
    const int rest = idx >> 6;
    const int t    = rest % 3;
    const int ki   = (rest / 3) % 36;
    const int c    = rest / 108;
    const int nrow = t * 1024 + c * 16 + (l & 15);
    const int kb   = ki * 32 + (l >> 4) * 8;
    short8 vh, vl;
#pragma unroll
    for (int j = 0; j < 8; ++j) {
        const int k = kb + j;
        float w = (k < 128) ? Wi[(size_t)nrow * 128 + k]
                            : Wh[(size_t)nrow * 1024 + (k - 128)];
        short h, lo2;
        f2pair(w, h, lo2);
        vh[j] = h; vl[j] = lo2;
    }
    *(short8*)(whi + (size_t)idx * 8) = vh;
    if (ki < 4) {
        const int xi = ((c * 4 + ki) * 3 + t) * 64 + l;
        *(short8*)(wlo_x + (size_t)xi * 8) = vl;
    }
}

// ---------- region-2 pipeline: depth 16, chunk-gated, XCD-rotated (R5) ----------
// Chunk kc in [0,8) covers ki = 4+4kc .. 7+4kc (producers [8kc, 8kc+8)).
// Block starts its sweep at r0 = c&7 == its XCD id: all same-XCD blocks
// share order (L2 multicast preserved) while different XCDs demand-fetch
// different eighths of the slice first. Do NOT desynchronize this rhythm:
// R8's early-issue fusion decorrelated readers and doubled FETCH (2.2x).
#define HCONS(S, KI) do { \
    short8 ah_ = *(short8*)&hb[S]; \
    const int fo_ = (((KI) * 3) * 64 + lane) * 8; \
    short8 b0_ = *(const short8*)(s_whi + fo_); \
    short8 b1_ = *(const short8*)(s_whi + fo_ + 512); \
    short8 b2_ = *(const short8*)(s_whi + fo_ + 1024); \
    aR  = MFMA(ah_, b0_, aR); \
    aZ  = MFMA(ah_, b1_, aZ); \
    aNh = MFMA(ah_, b2_, aNh); \
} while (0)

#define CH_ISSUE(LDFN, B, KC) do { \
    const short* hp_ = hrd + (size_t)(KC) * 16384; \
    hb[(B) + 0] = LDFN(hp_); \
    hb[(B) + 1] = LDFN(hp_ + 4096); \
    hb[(B) + 2] = LDFN(hp_ + 8192); \
    hb[(B) + 3] = LDFN(hp_ + 12288); \
} while (0)

#define CH_CONS(B, KC) do { \
    const int kb_ = 4 + 4 * (KC); \
    HCONS((B) + 0, kb_ + 0); \
    HCONS((B) + 1, kb_ + 1); \
    HCONS((B) + 2, kb_ + 2); \
    HCONS((B) + 3, kb_ + 3); \
} while (0)

#define SPIN_CH(KC) do { \
    while (ld_ws(&s_sub[KC]) < (unsigned)step) __builtin_amdgcn_s_sleep(2); \
} while (0)

#define REGION2(LDFN) do { \
    i32x4 hb[16]; \
    const int k0_ = r0;            const int k1_ = (r0 + 1) & 7; \
    const int k2_ = (r0 + 2) & 7;  const int k3_ = (r0 + 3) & 7; \
    const int k4_ = (r0 + 4) & 7;  const int k5_ = (r0 + 5) & 7; \
    const int k6_ = (r0 + 6) & 7;  const int k7_ = (r0 + 7) & 7; \
    SPIN_CH(k0_); CH_ISSUE(LDFN, 0,  k0_); \
    SPIN_CH(k1_); CH_ISSUE(LDFN, 4,  k1_); \
    SPIN_CH(k2_); CH_ISSUE(LDFN, 8,  k2_); \
    SPIN_CH(k3_); CH_ISSUE(LDFN, 12, k3_); \
    WAITVM(12); CH_CONS(0,  k0_); SPIN_CH(k4_); CH_ISSUE(LDFN, 0,  k4_); \
    WAITVM(12); CH_CONS(4,  k1_); SPIN_CH(k5_); CH_ISSUE(LDFN, 4,  k5_); \
    WAITVM(12); CH_CONS(8,  k2_); SPIN_CH(k6_); CH_ISSUE(LDFN, 8,  k6_); \
    WAITVM(12); CH_CONS(12, k3_); SPIN_CH(k7_); CH_ISSUE(LDFN, 12, k7_); \
    WAITVM(12); CH_CONS(0,  k4_); \
    WAITVM(8);  CH_CONS(4,  k5_); \
    WAITVM(4);  CH_CONS(8,  k6_); \
    WAITVM(0);  CH_CONS(12, k7_); \
} while (0)

// ---------- region-1 helpers (x part, 3-term hi/lo) ----------
#define R1TRIPLE(KI) do { \
    short8 ah_, al_; \
    _Pragma("unroll") \
    for (int j = 0; j < 8; ++j) { short h2_, l2_; f2pair(f[j], h2_, l2_); ah_[j] = h2_; al_[j] = l2_; } \
    const int fo_ = (((KI) * 3) * 64 + lane) * 8; \
    short8 b0_ = *(const short8*)(s_whi + fo_); \
    short8 b1_ = *(const short8*)(s_whi + fo_ + 512); \
    short8 b2_ = *(const short8*)(s_whi + fo_ + 1024); \
    aR  = MFMA(ah_, b0_, aR);  aR  = MFMA(ah_, L0r[KI], aR);  aR  = MFMA(al_, b0_, aR); \
    aZ  = MFMA(ah_, b1_, aZ);  aZ  = MFMA(ah_, L1r[KI], aZ);  aZ  = MFMA(al_, b1_, aZ); \
    aNi = MFMA(ah_, b2_, aNi); aNi = MFMA(ah_, L2r[KI], aNi); aNi = MFMA(al_, b2_, aNi); \
} while (0)

#define LOADF(KI) do { \
    const float* s_ = feats + ((size_t)brow * 159 + step) * 64 + (KI) * 32 + q * 8; \
    f32x4 a_ = ((const f32x4*)s_)[0], b_ = ((const f32x4*)s_)[1]; \
    _Pragma("unroll") for (int j = 0; j < 4; ++j) { f[j] = a_[j]; f[4 + j] = b_[j]; } \
} while (0)

#define LOADL(KI) do { \
    const float* s_ = labels + ((size_t)brow * 128 + step) * 64 + ((KI) - 2) * 32 + q * 8; \
    f32x4 a_ = ((const f32x4*)s_)[0], b_ = ((const f32x4*)s_)[1]; \
    _Pragma("unroll") for (int j = 0; j < 4; ++j) { f[j] = a_[j]; f[4 + j] = b_[j]; } \
} while (0)

#define LOADP(KI) do { \
    const u64* pp_ = (const u64*)(ps_f32 + (size_t)brow * 64 + ((KI) - 2) * 32 + q * 8); \
    _Pragma("unroll") for (int j = 0; j < 4; ++j) { \
        u64 v_ = ldq_dev(pp_ + j); \
        f[2 * j]     = __uint_as_float((unsigned)v_); \
        f[2 * j + 1] = __uint_as_float((unsigned)(v_ >> 32)); } \
} while (0)

// ---------- main persistent kernel (R5 skeleton; decoder chain cleanup) ----------
//  - h(t) in its OWN 1 MB slot; far-atomic swap publish, drain deferred into
//    next-step region1; consumer sc0 loads -> XCD-L2 multicast.
//  - Encoder steps: R5 VERBATIM (this rhythm preserves L2 sharing; R8 lesson).
//  - Decoder steps (cleanup, certified-redundant waits removed):
//    (a) NO hflag re-poll: previous step's ps phase already observed ALL 64
//        hflag >= step (grp_hfl wait with tgt == step) + barrier. Ring-2 WAR
//        transitivity is also certified by that same ps-phase wait.
//    (b) pflag wait: per-wave poll of producers [8wv,8wv+8) with a prefetch
//        seed issued at step top, NO block barrier (wave wv's LOADP reads
//        only those producers' ps rows).
__global__ __launch_bounds__(512, 2) void gru_main(
    const float* __restrict__ feats, const float* __restrict__ labels,
    const float* __restrict__ bi,    const float* __restrict__ bh,
    const float* __restrict__ Wd,    const float* __restrict__ bd,
    const short* __restrict__ whi_sw, const short* __restrict__ wlo_x,
    short* __restrict__ h16,         float* __restrict__ ps_f32,
    float* __restrict__ out,
    unsigned* __restrict__ hflag,    // [4r][64c] @64B
    unsigned* __restrict__ pflag,    // [4r][64c] @64B
    int nslots)                      // 160 = fresh-per-step (cached), 2 = ring (nc)
{
    __shared__ short s_whi[SLAB_ELEMS];   // 108 KB resident W_hi slab (fragment order)
    __shared__ float s_ps[2048];          // ps-phase h staging (2 rows x 1024)
    __shared__ short s_tr[8][16][18];     // epilogue transpose tiles (padded: bank-safe)
    __shared__ unsigned s_sub[8];         // chunk ready: latest step confirmed
    __shared__ unsigned s_arrD, s_arrI;   // publish arrival counters (deferred/immediate)

    const int tid  = threadIdx.x;
    const int lane = tid & 63;
    const int wv   = tid >> 6;            // wave 0..7
    const int q    = lane >> 4;
    const int n16  = lane & 15;
    const int c    = blockIdx.x & 63;     // out-group: h-cols [16c, 16c+16)
    const int r    = blockIdx.x >> 6;     // batch-group: rows [128r, 128r+128)
    const int r0   = c & 7;               // XCD id: rotation start chunk
    const bool cached = (nslots > 2);

    // init sync state + stage W_hi slab
    if (tid < 8) s_sub[tid] = 0;
    if (tid == 8) s_arrD = 0;
    if (tid == 9) s_arrI = 0;
    {
        const f32x4* src = (const f32x4*)(whi_sw + (size_t)c * SLAB_ELEMS);
        f32x4* dst = (f32x4*)s_whi;
        for (int i = tid; i < SLAB_ELEMS / 8; i += 512) dst[i] = src[i];
    }
    __syncthreads();

    const int mbase = r * 128 + wv * 16;  // this wave's 16 batch rows (global)
    const int brow  = mbase + n16;        // A-fragment row for this lane
    const int row_r = c * 16 + n16;       // gate row == D col
    const float bias_r  = bi[row_r] + bh[row_r];
    const float bias_z  = bi[1024 + row_r] + bh[1024 + row_r];
    const float bias_ni = bi[2048 + row_r];
    const float bias_nh = bh[2048 + row_r];

    unsigned* my_hflag = hflag + (r * 64 + c) * FS;
    unsigned* my_pflag = pflag + (r * 64 + c) * FS;
    const unsigned* hfp     = hflag + (r * 64 + 8 * wv + (lane & 7)) * FS;  // wave's 8 h-producers
    const unsigned* pfp     = pflag + (r * 64 + 8 * wv + (lane & 7)) * FS;  // wave's 8 ps-producers
    const unsigned* grp_hfl = hflag + (r * 64) * FS;

    // hoist region-1 W_lo fragments (step-invariant): 12 x short8 = 48 VGPRs
    short8 L0r[4], L1r[4], L2r[4];
#pragma unroll
    for (int ki = 0; ki < 4; ++ki) {
        const short* base = wlo_x + (size_t)(((c * 4 + ki) * 3) * 64 + lane) * 8;
        L0r[ki] = *(const short8*)(base);
        L1r[ki] = *(const short8*)(base + 512);
        L2r[ki] = *(const short8*)(base + 1024);
    }

    float hold[4] = {0.f, 0.f, 0.f, 0.f};  // h carried fp32 in-register

    for (int step = 0; step < NSTEPS; ++step) {
        const bool dec = (step >= SENC);
        const unsigned tgt = (unsigned)(step + 1);
        const int rslot = cached ? step       : (step & 1);
        const int wslot = cached ? (step + 1) : ((step + 1) & 1);
        const short* hrd = h16 + (size_t)rslot * HB16 + (size_t)r * XSLICE
                         + (size_t)(wv * 16 + n16) * 16 + (q & 1) * 8 + (q >> 1) * 2048;
        short* hwr = h16 + (size_t)wslot * HB16 + (size_t)r * XSLICE;

        // decoder: pflag prefetch seed (RT hides under region1's F-triples)
        unsigned pf_pre = 0xFFFFFFFFu;
        if (dec) pf_pre = ldu_dev(pfp);

        floatx4 aR  = (floatx4){bias_r,  bias_r,  bias_r,  bias_r};
        floatx4 aZ  = (floatx4){bias_z,  bias_z,  bias_z,  bias_z};
        floatx4 aNi = (floatx4){bias_ni, bias_ni, bias_ni, bias_ni};
        floatx4 aNh = (floatx4){bias_nh, bias_nh, bias_nh, bias_nh};

        // ---- region 1 (x part), deferred publish-finalize in the middle ----
        {
            float f[8];
            LOADF(0); R1TRIPLE(0);
            LOADF(1); R1TRIPLE(1);

            // finalize h(step) publish (swaps issued at epilogue of step-1):
            // drain hides under region1 compute; flag lands early.
            if (step > 0 && step <= SENC - 1) {
                WAITVM(0);
                if (lane == 0) {
                    unsigned old = add_ws(&s_arrD, 1u);
                    if (old == 8u * (unsigned)step - 1u)
                        stu_dev(my_hflag, (unsigned)step);
                }
            }

            if (!dec) {
                LOADL(2); R1TRIPLE(2);
                LOADL(3); R1TRIPLE(3);
            } else {
                // ps(step) ready: per-wave seeded poll, NO barrier
                if (!__all(pf_pre >= (unsigned)step)) {
                    while (!__all(ldu_dev(pfp) >= (unsigned)step))
                        __builtin_amdgcn_s_sleep(2);
                }
                LOADP(2); R1TRIPLE(2);
                LOADP(3); R1TRIPLE(3);
            }
        }

        // ---- h-ready gate + chunk-gated, XCD-rotated region 2 ----
        if (step > 0) {
            if (!dec) {
                // encoder: distributed per-wave poll (R5)
                while (!__all(ldu_dev(hfp) >= (unsigned)step))
                    __builtin_amdgcn_s_sleep(2);
            }
            // decoder: previous ps phase (grp_hfl wait, tgt==step, + barrier)
            // already certified all 64 hflag >= step -> no re-poll.
            if (lane == 0) st_ws(&s_sub[wv], (unsigned)step);
            if (cached) { REGION2(ld_sc0_16); }   // L2-cached; XCD multicast
            else        { REGION2(ld_nc16); }     // ring-2 fallback: coherence-point direct
        }

        // ---- epilogue: GRU update; far-atomic publish of own tile ----
        {
#pragma unroll
            for (int i = 0; i < 4; ++i) {
                float rr = sigm(aR[i]);
                float zz = sigm(aZ[i]);
                float nn = tanh_fast(aNi[i] + rr * aNh[i]);
                float hv = (1.0f - zz) * nn + zz * hold[i];
                hold[i] = hv;
                s_tr[wv][q * 4 + i][n16] = f2bf(hv);   // D row = q*4+i, col = n16
            }
            WAITLGKM;
            const int rr2 = lane >> 2, seg = lane & 3;
            u64 v = *(const u64*)&s_tr[wv][rr2][seg * 4];
            st_swap8(hwr + (size_t)c * 2048 + (size_t)(wv * 16 + rr2) * 16 + seg * 4, v);
            if (step >= SENC - 1) {                    // immediate publish (ps needs it)
                WAITVM(0);
                if (lane == 0) {
                    unsigned old = add_ws(&s_arrI, 1u);
                    if (old == 8u * (unsigned)(step - (SENC - 1) + 1) - 1u)
                        stu_dev(my_hflag, tgt);
                }
            }
        }

        // ---- ps phase: after encoder (step 127) and every decoder step ----
        if (step >= SENC - 1) {
            const int ot = step - (SENC - 1);          // output time 0..31
            const int prow0 = r * 128 + 2 * c;         // this block's 2 ps rows (global)
            if (wv == 0) {                              // need ALL producers' h rows
                while (ldu_dev(grp_hfl + lane * FS) < tgt)
                    __builtin_amdgcn_s_sleep(2);
            }
            __syncthreads();
            if (tid < 256) {                            // 2 rows x 1024 cols, tile-major gather
                const int rl = tid >> 7, rest = tid & 127;
                const int ct = rest >> 1, half = rest & 1;
                const short* src = hwr + (size_t)ct * 2048
                                 + (size_t)(2 * c + rl) * 16 + half * 8;
                i32x4 v = ld_nc16(src);
                WAITVM(0);
                short8 s = *(short8*)&v;
#pragma unroll
                for (int j = 0; j < 8; ++j)
                    s_ps[rl * 1024 + ct * 16 + half * 8 + j] = bf2f(s[j]);
            }
            __syncthreads();
            // dedup'd dot: each thread does BOTH rows for (o, K-eighth e)
            const int o = tid >> 3, e = tid & 7;
            const float* wrow = Wd + (size_t)o * 1024;
            float acc0 = 0.0f, acc1 = 0.0f;
#pragma unroll 8
            for (int j = 0; j < 32; ++j) {
                const int k = j * 32 + e * 4;
                f32x4 w  = *(const f32x4*)(wrow + k);
                f32x4 a4 = *(const f32x4*)(s_ps + k);
                f32x4 b4 = *(const f32x4*)(s_ps + 1024 + k);
                acc0 += a4[0] * w[0] + a4[1] * w[1] + a4[2] * w[2] + a4[3] * w[3];
                acc1 += b4[0] * w[0] + b4[1] * w[1] + b4[2] * w[2] + b4[3] * w[3];
            }
            acc0 += __shfl_xor(acc0, 1); acc0 += __shfl_xor(acc0, 2); acc0 += __shfl_xor(acc0, 4);
            acc1 += __shfl_xor(acc1, 1); acc1 += __shfl_xor(acc1, 2); acc1 += __shfl_xor(acc1, 4);
            if (e == 0) {
                float v0 = acc0 + bd[o];
                float v1 = acc1 + bd[o];
                out[((size_t)ot * 512 + prow0)     * 64 + o] = v0;
                out[((size_t)ot * 512 + prow0 + 1) * 64 + o] = v1;
                st_swap4(ps_f32 + (size_t)prow0       * 64 + o, __float_as_uint(v0));
                st_swap4(ps_f32 + (size_t)(prow0 + 1) * 64 + o, __float_as_uint(v1));
            }
            WAITVM(0);
            __syncthreads();
            if (tid == 0) stu_dev(my_pflag, tgt);      // ps(step+1) published
        }
    }
}

extern "C" void kernel_launch(void* const* d_in, const int* in_sizes, int n_in,
                              void* d_out, int out_size, void* d_ws, size_t ws_size,
                              hipStream_t stream) {
    const float* feats  = (const float*)d_in[0];
    const float* labels = (const float*)d_in[1];
    const float* Wi     = (const float*)d_in[2];
    const float* Wh     = (const float*)d_in[3];
    const float* bi     = (const float*)d_in[4];
    const float* bh     = (const float*)d_in[5];
    const float* Wd     = (const float*)d_in[6];
    const float* bd     = (const float*)d_in[7];
    float* out = (float*)d_out;

    char* ws = (char*)d_ws;
    short*    whi_sw = (short*)(ws);                   //  7,077,888 B
    short*    wlo_x  = (short*)(ws + 7077888);         //    786,432 B
    float*    ps_f32 = (float*)(ws + 7864320);         //    131,072 B
    unsigned* pflag  = (unsigned*)(ws + 7995392);      //     16,384 B (4r x 64c x 64B)
    unsigned* hflag  = (unsigned*)(ws + 8011776);      //     16,384 B (4r x 64c x 64B)
    short*    h16    = (short*)(ws + 8388608);         //  nslots x 1 MB h slots

    // cached mode needs slots 0..159 (slot t = h(t)); fallback = 2-slot ring + nc reads
    const size_t need = 8388608ull + 160ull * 1048576ull;  // 176,160,768 B
    int nslots = (ws_size >= need) ? 160 : 2;

    // zero flag state (pflag + hflag)
    hipMemsetAsync(ws + 7995392, 0, 32768, stream);

    setup_swizzle<<<FRAG_TOTAL / 256, 256, 0, stream>>>(Wi, Wh, whi_sw, wlo_x);

    void* args[] = {(void*)&feats, (void*)&labels, (void*)&bi, (void*)&bh,
                    (void*)&Wd, (void*)&bd, (void*)&whi_sw, (void*)&wlo_x,
                    (void*)&h16, (void*)&ps_f32, (void*)&out,
                    (void*)&hflag, (void*)&pflag, (void*)&nslots};
    hipLaunchCooperativeKernel(reinterpret_cast<void*>(gru_main),
                               dim3(256), dim3(512), args, 0, stream);
}